// Round 1
// baseline (2779.092 us; speedup 1.0000x reference)
//
#include <hip/hip_runtime.h>

typedef __bf16 bf16x8 __attribute__((ext_vector_type(8)));
typedef float f32x16 __attribute__((ext_vector_type(16)));

#define LN_EPS 1e-5f

__device__ __forceinline__ unsigned f2bf_rne(float f) {
    unsigned x = __float_as_uint(f);
    return (x + 0x7fffu + ((x >> 16) & 1u)) >> 16;  // round-to-nearest-even, finite inputs
}

// ---------------------------------------------------------------------------
// Pack conv_w fp32 (4,27,128,128) -> bf16, K-packed by 8: Wp[oc][k>>3][n][k&7]
// so MFMA B-fragments are contiguous 16B in LDS.
// ---------------------------------------------------------------------------
__global__ void pack_w_kernel(const float* __restrict__ cw, unsigned short* __restrict__ Wp, int E) {
    int idx = blockIdx.x * 256 + threadIdx.x;
    if (idx >= E) return;
    float v = cw[idx];
    int n  = idx & 127;
    int c  = (idx >> 7) & 127;
    int oc = idx >> 14;
    Wp[oc * 16384 + (c >> 3) * 1024 + n * 8 + (c & 7)] = (unsigned short)f2bf_rne(v);
}

// ---------------------------------------------------------------------------
// Encoder: f = relu(LN(gp @ w_enc + b_enc)), scatter-add into voxel sums.
// One wave per point; lane handles channels {lane, lane+64}.
// ---------------------------------------------------------------------------
__global__ __launch_bounds__(256) void encode_kernel(
    const float* __restrict__ gp, const float* __restrict__ w_enc,
    const float* __restrict__ b_enc, const float* __restrict__ ln_g,
    const float* __restrict__ ln_b, const int* __restrict__ inv_idx,
    float* __restrict__ vsum, float* __restrict__ cnt, int N)
{
    int p = blockIdx.x * 4 + (threadIdx.x >> 6);
    int lane = threadIdx.x & 63;
    if (p >= N) return;
    float gv[14];
#pragma unroll
    for (int i = 0; i < 14; ++i) gv[i] = gp[p * 14 + i];
    float f0 = b_enc[lane], f1 = b_enc[lane + 64];
#pragma unroll
    for (int i = 0; i < 14; ++i) {
        f0 = fmaf(gv[i], w_enc[i * 128 + lane], f0);
        f1 = fmaf(gv[i], w_enc[i * 128 + lane + 64], f1);
    }
    float s = f0 + f1;
#pragma unroll
    for (int off = 32; off; off >>= 1) s += __shfl_xor(s, off);
    float mean = s * 0.0078125f;
    float d0 = f0 - mean, d1 = f1 - mean;
    float v = d0 * d0 + d1 * d1;
#pragma unroll
    for (int off = 32; off; off >>= 1) v += __shfl_xor(v, off);
    float rs = rsqrtf(v * 0.0078125f + LN_EPS);
    float h0 = d0 * rs * ln_g[lane] + ln_b[lane];
    float h1 = d1 * rs * ln_g[lane + 64] + ln_b[lane + 64];
    h0 = h0 > 0.f ? h0 : 0.f;
    h1 = h1 > 0.f ? h1 : 0.f;
    int vx = inv_idx[p];
    atomicAdd(&vsum[vx * 128 + lane], h0);
    atomicAdd(&vsum[vx * 128 + lane + 64], h1);
    if (lane == 0) atomicAdd(&cnt[vx], 1.0f);
}

// ---------------------------------------------------------------------------
// Voxel mean: A_bf16 = vsum / cnt
// ---------------------------------------------------------------------------
__global__ void vox_mean_kernel(const float* __restrict__ vsum, const float* __restrict__ cnt,
                                unsigned short* __restrict__ out, int total4) {
    int idx = blockIdx.x * 256 + threadIdx.x;
    if (idx >= total4) return;
    int e0 = idx * 4;
    float r = 1.f / cnt[e0 >> 7];
    float4 v = *(const float4*)(vsum + e0);
    uint2 pk;
    pk.x = f2bf_rne(v.x * r) | (f2bf_rne(v.y * r) << 16);
    pk.y = f2bf_rne(v.z * r) | (f2bf_rne(v.w * r) << 16);
    *(uint2*)(out + e0) = pk;
}

// ---------------------------------------------------------------------------
// Submanifold conv: y[m] = sum_o mask[m,o] * x[nbr[m,o]] @ W[o]
// Tile: 128 voxels x 128 ch. 4 waves, wave w owns rows [32w,32w+32).
// Also accumulates per-channel sum/sumsq for BN into stats via atomics.
// ---------------------------------------------------------------------------
__global__ __launch_bounds__(256, 2) void subm_conv_kernel(
    const unsigned short* __restrict__ xin,   // M x 128 bf16
    const unsigned short* __restrict__ Wp,    // 27 x 16 x 128 x 8 bf16 packed
    const int* __restrict__ nbr_idx, const float* __restrict__ nbr_mask,
    float* __restrict__ yout, float* __restrict__ stats, int M)
{
    __shared__ uint4 XsRaw[2048];  // 128 rows x 16 chunks of 16B, XOR-swizzled
    __shared__ uint4 WsRaw[2048];  // [kb][n] chunks

    const int tid = threadIdx.x;
    const int lane = tid & 63;
    const int w = tid >> 6;
    const int m0 = blockIdx.x * 128;
    const int rw = w * 32;
    const int sub = tid & 15;
    const int rr = tid >> 4;
    const int q = lane >> 5;
    const int l31 = lane & 31;
    const int l15 = lane & 15;

    f32x16 acc[4];
#pragma unroll
    for (int t = 0; t < 4; ++t)
#pragma unroll
        for (int r = 0; r < 16; ++r) acc[t][r] = 0.f;

    const uint4* xin4 = (const uint4*)xin;

    for (int o = 0; o < 27; ++o) {
        int pred = 0;
        if (tid < 128) {
            int m = m0 + tid;
            if (m < M) pred = (nbr_mask[m * 27 + o] != 0.f);
        }
        if (!__syncthreads_or(pred)) continue;  // barrier also covers WAR on LDS

        // ---- stage gathered X rows (masked) ----
#pragma unroll
        for (int rep = 0; rep < 8; ++rep) {
            int row = rep * 16 + rr;
            int m = m0 + row;
            uint4 v = make_uint4(0u, 0u, 0u, 0u);
            if (m < M) {
                float mk = nbr_mask[m * 27 + o];
                if (mk != 0.f) {
                    int g = nbr_idx[m * 27 + o];
                    v = xin4[g * 16 + sub];
                }
            }
            XsRaw[row * 16 + (sub ^ (row & 15))] = v;
        }
        // ---- stage W[o] ----
        const uint4* WpO4 = (const uint4*)(Wp + o * 16384);
#pragma unroll
        for (int rep = 0; rep < 8; ++rep)
            WsRaw[rep * 256 + tid] = WpO4[rep * 256 + tid];
        __syncthreads();

        // ---- MFMA over K=128 (8 steps of 16) ----
#pragma unroll
        for (int ks = 0; ks < 8; ++ks) {
            int kb = (ks << 1) | q;
            bf16x8 a = ((const bf16x8*)XsRaw)[(rw + l31) * 16 + (kb ^ l15)];
#pragma unroll
            for (int tn = 0; tn < 4; ++tn) {
                bf16x8 b = ((const bf16x8*)WsRaw)[kb * 128 + tn * 32 + l31];
                acc[tn] = __builtin_amdgcn_mfma_f32_32x32x16_bf16(a, b, acc[tn], 0, 0, 0);
            }
        }
    }
    __syncthreads();

    // ---- epilogue: store y + BN stats ----
#pragma unroll
    for (int tn = 0; tn < 4; ++tn) {
        int col = tn * 32 + l31;
        float s = 0.f, sq = 0.f;
#pragma unroll
        for (int r = 0; r < 16; ++r) {
            int rloc = (r & 3) + 8 * (r >> 2) + 4 * q + rw;
            int grow = m0 + rloc;
            float v = acc[tn][r];
            if (grow < M) yout[grow * 128 + col] = v;
            s += v; sq += v * v;
        }
        s += __shfl_xor(s, 32);
        sq += __shfl_xor(sq, 32);
        if (lane < 32) {
            atomicAdd(&stats[col], s);
            atomicAdd(&stats[128 + col], sq);
        }
    }
}

// ---------------------------------------------------------------------------
// BN (batch stats) + ReLU -> bf16 (optionally + residual)
// ---------------------------------------------------------------------------
__global__ void bn_relu_kernel(const float* __restrict__ y, const float* __restrict__ stats,
                               const float* __restrict__ g, const float* __restrict__ b,
                               unsigned short* __restrict__ out, int total4, float invM) {
    int idx = blockIdx.x * 256 + threadIdx.x;
    if (idx >= total4) return;
    int e0 = idx * 4;
    int c0 = e0 & 127;
    float4 yv = *(const float4*)(y + e0);
    float h[4];
    const float* yp = (const float*)&yv;
#pragma unroll
    for (int j = 0; j < 4; ++j) {
        int c = c0 + j;
        float mean = stats[c] * invM;
        float var = stats[128 + c] * invM - mean * mean;
        float sc = g[c] * rsqrtf(var + LN_EPS);
        float sh = b[c] - mean * sc;
        float vv = yp[j] * sc + sh;
        h[j] = vv > 0.f ? vv : 0.f;
    }
    uint2 pk;
    pk.x = f2bf_rne(h[0]) | (f2bf_rne(h[1]) << 16);
    pk.y = f2bf_rne(h[2]) | (f2bf_rne(h[3]) << 16);
    *(uint2*)(out + e0) = pk;
}

__global__ void bn_relu_res_kernel(const float* __restrict__ y, const float* __restrict__ stats,
                                   const float* __restrict__ g, const float* __restrict__ b,
                                   const unsigned short* __restrict__ idn,
                                   unsigned short* __restrict__ out, int total4, float invM) {
    int idx = blockIdx.x * 256 + threadIdx.x;
    if (idx >= total4) return;
    int e0 = idx * 4;
    int c0 = e0 & 127;
    float4 yv = *(const float4*)(y + e0);
    uint2 iv = *(const uint2*)(idn + e0);
    float id[4];
    id[0] = __uint_as_float(iv.x << 16);
    id[1] = __uint_as_float(iv.x & 0xffff0000u);
    id[2] = __uint_as_float(iv.y << 16);
    id[3] = __uint_as_float(iv.y & 0xffff0000u);
    float h[4];
    const float* yp = (const float*)&yv;
#pragma unroll
    for (int j = 0; j < 4; ++j) {
        int c = c0 + j;
        float mean = stats[c] * invM;
        float var = stats[128 + c] * invM - mean * mean;
        float sc = g[c] * rsqrtf(var + LN_EPS);
        float sh = b[c] - mean * sc;
        float vv = yp[j] * sc + sh + id[j];
        h[j] = vv > 0.f ? vv : 0.f;
    }
    uint2 pk;
    pk.x = f2bf_rne(h[0]) | (f2bf_rne(h[1]) << 16);
    pk.y = f2bf_rne(h[2]) | (f2bf_rne(h[3]) << 16);
    *(uint2*)(out + e0) = pk;
}

// ---------------------------------------------------------------------------
// Head: out = gp[:,:14] + relu(A[inv] @ w1 + b1) @ w2 + b2.  One wave/point.
// ---------------------------------------------------------------------------
__global__ __launch_bounds__(256) void head_kernel(
    const float* __restrict__ gp, const unsigned short* __restrict__ A,
    const int* __restrict__ inv_idx, const float* __restrict__ w1,
    const float* __restrict__ b1, const float* __restrict__ w2,
    const float* __restrict__ b2, float* __restrict__ out, int N)
{
    int p = blockIdx.x * 4 + (threadIdx.x >> 6);
    int lane = threadIdx.x & 63;
    if (p >= N) return;
    int vx = inv_idx[p];
    unsigned u = *(const unsigned*)(A + vx * 128 + lane * 2);
    float pf0 = __uint_as_float(u << 16);
    float pf1 = __uint_as_float(u & 0xffff0000u);
    float t = b1[lane];
#pragma unroll
    for (int c = 0; c < 128; c += 2) {
        float pa = __shfl(pf0, c >> 1);
        float pb = __shfl(pf1, c >> 1);
        t = fmaf(pa, w1[c * 64 + lane], t);
        t = fmaf(pb, w1[(c + 1) * 64 + lane], t);
    }
    t = t > 0.f ? t : 0.f;
    int cl = lane < 14 ? lane : 13;
    float o = b2[cl] + gp[p * 14 + cl];
#pragma unroll
    for (int k = 0; k < 64; ++k) {
        float tv = __shfl(t, k);
        o = fmaf(tv, w2[k * 14 + cl], o);
    }
    if (lane < 14) out[p * 14 + lane] = o;
}

// ---------------------------------------------------------------------------
extern "C" void kernel_launch(void* const* d_in, const int* in_sizes, int n_in,
                              void* d_out, int out_size, void* d_ws, size_t ws_size,
                              hipStream_t stream) {
    const float* gp       = (const float*)d_in[0];
    const float* w_enc    = (const float*)d_in[1];
    const float* b_enc    = (const float*)d_in[2];
    const float* ln_g     = (const float*)d_in[3];
    const float* ln_b     = (const float*)d_in[4];
    const float* conv_w   = (const float*)d_in[5];
    const float* bn_g     = (const float*)d_in[6];
    const float* bn_b     = (const float*)d_in[7];
    const float* w1       = (const float*)d_in[8];
    const float* b1       = (const float*)d_in[9];
    const float* w2       = (const float*)d_in[10];
    const float* b2       = (const float*)d_in[11];
    const float* nbr_mask = (const float*)d_in[12];
    const int*   inv_idx  = (const int*)d_in[13];
    const int*   nbr_idx  = (const int*)d_in[14];

    const int N = in_sizes[0] / 14;
    const int M = in_sizes[12] / 27;

    char* ws = (char*)d_ws;
    size_t off = 0;
    unsigned short* Wp = (unsigned short*)(ws + off); off += (size_t)4 * 27 * 16384 * 2;
    unsigned short* A  = (unsigned short*)(ws + off); off += (size_t)M * 128 * 2;
    unsigned short* H  = (unsigned short*)(ws + off); off += (size_t)M * 128 * 2;
    float* Yraw  = (float*)(ws + off); off += (size_t)M * 128 * 4;  // also voxel-sum accumulator
    float* cnt   = (float*)(ws + off); off += (size_t)M * 4;
    float* stats = (float*)(ws + off); off += 4 * 256 * 4;

    // zero voxel sums + counts + BN stats (contiguous region)
    hipMemsetAsync(Yraw, 0, (size_t)M * 128 * 4 + (size_t)M * 4 + 4 * 256 * 4, stream);

    const int E = 4 * 27 * 128 * 128;
    pack_w_kernel<<<(E + 255) / 256, 256, 0, stream>>>(conv_w, Wp, E);
    encode_kernel<<<(N + 3) / 4, 256, 0, stream>>>(gp, w_enc, b_enc, ln_g, ln_b, inv_idx, Yraw, cnt, N);
    const int total4 = M * 32;
    vox_mean_kernel<<<(total4 + 255) / 256, 256, 0, stream>>>(Yraw, cnt, A, total4);

    const float invM = 1.f / (float)M;
    for (int blk = 0; blk < 2; ++blk) {
        int c0 = 2 * blk, c1 = 2 * blk + 1;
        subm_conv_kernel<<<(M + 127) / 128, 256, 0, stream>>>(
            A, Wp + (size_t)c0 * 27 * 16384, nbr_idx, nbr_mask, Yraw, stats + c0 * 256, M);
        bn_relu_kernel<<<(total4 + 255) / 256, 256, 0, stream>>>(
            Yraw, stats + c0 * 256, bn_g + c0 * 128, bn_b + c0 * 128, H, total4, invM);
        subm_conv_kernel<<<(M + 127) / 128, 256, 0, stream>>>(
            H, Wp + (size_t)c1 * 27 * 16384, nbr_idx, nbr_mask, Yraw, stats + c1 * 256, M);
        bn_relu_res_kernel<<<(total4 + 255) / 256, 256, 0, stream>>>(
            Yraw, stats + c1 * 256, bn_g + c1 * 128, bn_b + c1 * 128, A, A, total4, invM);
    }
    head_kernel<<<(N + 3) / 4, 256, 0, stream>>>(gp, A, inv_idx, w1, b1, w2, b2, (float*)d_out, N);
}

// Round 2
// 1864.497 us; speedup vs baseline: 1.4905x; 1.4905x over previous
//
#include <hip/hip_runtime.h>

typedef __bf16 bf16x8 __attribute__((ext_vector_type(8)));
typedef float f32x16 __attribute__((ext_vector_type(16)));

#define LN_EPS 1e-5f
#define AS1 __attribute__((address_space(1)))
#define AS3 __attribute__((address_space(3)))

__device__ __forceinline__ unsigned f2bf_rne(float f) {
    unsigned x = __float_as_uint(f);
    return (x + 0x7fffu + ((x >> 16) & 1u)) >> 16;  // round-to-nearest-even, finite inputs
}

// ---------------------------------------------------------------------------
// Pack conv_w fp32 (4,27,128,128) -> bf16, K-packed by 8: Wp[oc][k>>3][n][k&7]
// so MFMA B-fragments are contiguous 16B.
// ---------------------------------------------------------------------------
__global__ void pack_w_kernel(const float* __restrict__ cw, unsigned short* __restrict__ Wp, int E) {
    int idx = blockIdx.x * 256 + threadIdx.x;
    if (idx >= E) return;
    float v = cw[idx];
    int n  = idx & 127;
    int c  = (idx >> 7) & 127;
    int oc = idx >> 14;
    Wp[oc * 16384 + (c >> 3) * 1024 + n * 8 + (c & 7)] = (unsigned short)f2bf_rne(v);
}

// ---------------------------------------------------------------------------
// Prep: gather table T[o][m] = found ? nbr_idx : M (dummy zero row),
// and per-128-tile activity bitmask act[tile].
// ---------------------------------------------------------------------------
__global__ void prep_nbr_kernel(const int* __restrict__ nbr_idx, const float* __restrict__ nbr_mask,
                                int* __restrict__ T, unsigned* __restrict__ act, int M) {
    int m = blockIdx.x * 256 + threadIdx.x;
    if (m >= M) return;
    unsigned bits = 0;
#pragma unroll
    for (int o = 0; o < 27; ++o) {
        bool f = nbr_mask[m * 27 + o] != 0.f;
        int g = f ? nbr_idx[m * 27 + o] : M;
        T[o * M + m] = g;
        bits |= (f ? 1u : 0u) << o;
    }
    atomicOr(&act[m >> 7], bits);
}

// ---------------------------------------------------------------------------
// Encoder: f = relu(LN(gp @ w_enc + b_enc)), scatter-add into voxel sums.
// ---------------------------------------------------------------------------
__global__ __launch_bounds__(256) void encode_kernel(
    const float* __restrict__ gp, const float* __restrict__ w_enc,
    const float* __restrict__ b_enc, const float* __restrict__ ln_g,
    const float* __restrict__ ln_b, const int* __restrict__ inv_idx,
    float* __restrict__ vsum, float* __restrict__ cnt, int N)
{
    int p = blockIdx.x * 4 + (threadIdx.x >> 6);
    int lane = threadIdx.x & 63;
    if (p >= N) return;
    float gv[14];
#pragma unroll
    for (int i = 0; i < 14; ++i) gv[i] = gp[p * 14 + i];
    float f0 = b_enc[lane], f1 = b_enc[lane + 64];
#pragma unroll
    for (int i = 0; i < 14; ++i) {
        f0 = fmaf(gv[i], w_enc[i * 128 + lane], f0);
        f1 = fmaf(gv[i], w_enc[i * 128 + lane + 64], f1);
    }
    float s = f0 + f1;
#pragma unroll
    for (int off = 32; off; off >>= 1) s += __shfl_xor(s, off);
    float mean = s * 0.0078125f;
    float d0 = f0 - mean, d1 = f1 - mean;
    float v = d0 * d0 + d1 * d1;
#pragma unroll
    for (int off = 32; off; off >>= 1) v += __shfl_xor(v, off);
    float rs = rsqrtf(v * 0.0078125f + LN_EPS);
    float h0 = d0 * rs * ln_g[lane] + ln_b[lane];
    float h1 = d1 * rs * ln_g[lane + 64] + ln_b[lane + 64];
    h0 = h0 > 0.f ? h0 : 0.f;
    h1 = h1 > 0.f ? h1 : 0.f;
    int vx = inv_idx[p];
    atomicAdd(&vsum[vx * 128 + lane], h0);
    atomicAdd(&vsum[vx * 128 + lane + 64], h1);
    if (lane == 0) atomicAdd(&cnt[vx], 1.0f);
}

// ---------------------------------------------------------------------------
// Voxel mean: A_bf16 = vsum / cnt
// ---------------------------------------------------------------------------
__global__ void vox_mean_kernel(const float* __restrict__ vsum, const float* __restrict__ cnt,
                                unsigned short* __restrict__ out, int total4) {
    int idx = blockIdx.x * 256 + threadIdx.x;
    if (idx >= total4) return;
    int e0 = idx * 4;
    float r = 1.f / cnt[e0 >> 7];
    float4 v = *(const float4*)(vsum + e0);
    uint2 pk;
    pk.x = f2bf_rne(v.x * r) | (f2bf_rne(v.y * r) << 16);
    pk.y = f2bf_rne(v.z * r) | (f2bf_rne(v.w * r) << 16);
    *(uint2*)(out + e0) = pk;
}

// ---------------------------------------------------------------------------
// Submanifold conv v2: y[m] = sum_o x[T[o][m]] @ W[o]   (T==M -> zero row)
// 128 voxels x 128 ch per block, 4 waves. A gathered straight to registers
// (no LDS), W[o] staged async via global_load_lds. Tile-level offset skip
// via precomputed bitmask (no per-offset syncthreads_or).
// ---------------------------------------------------------------------------
__global__ __launch_bounds__(256, 4) void subm_conv_kernel(
    const unsigned short* __restrict__ xin,   // (M+1) x 128 bf16, row M zeros
    const unsigned short* __restrict__ Wp,    // 27 x 16 x 128 x 8 bf16 packed
    const int* __restrict__ T, const unsigned* __restrict__ act,
    float* __restrict__ yout, float* __restrict__ stats, int M)
{
    __shared__ uint4 Ws[2048];  // W[o]: [kb][n] 16B chunks, 32 KB

    const int tid = threadIdx.x;
    const int lane = tid & 63;
    const int w = tid >> 6;
    const int m0 = blockIdx.x * 128;
    const int rw = w * 32;
    const int q = lane >> 5;
    const int l31 = lane & 31;
    int myrow = m0 + rw + l31;
    if (myrow >= M) myrow = M - 1;  // gather table guard (stores guarded below)

    f32x16 acc[4];
#pragma unroll
    for (int t = 0; t < 4; ++t)
#pragma unroll
        for (int r = 0; r < 16; ++r) acc[t][r] = 0.f;

    const uint4* xin4 = (const uint4*)xin;
    unsigned amask = act[blockIdx.x];

    while (amask) {
        int o = __ffs(amask) - 1;
        amask &= amask - 1;

        __syncthreads();  // Ws free (prev offset's MFMA reads done)

        // ---- async stage W[o] -> LDS (no VGPR cost) ----
        const uint4* WpO4 = (const uint4*)Wp + o * 2048;
#pragma unroll
        for (int rep = 0; rep < 8; ++rep) {
            __builtin_amdgcn_global_load_lds(
                (const AS1 unsigned int*)(WpO4 + rep * 256 + tid),
                (AS3 unsigned int*)(Ws + rep * 256 + w * 64), 16, 0, 0);
        }

        // ---- gather this wave's 32 A-rows straight to registers ----
        int g = T[o * M + myrow];
        uint4 af[8];
#pragma unroll
        for (int j = 0; j < 8; ++j) af[j] = xin4[g * 16 + 2 * j + q];

        __syncthreads();  // barrier drains vmcnt: W in LDS

        // ---- MFMA over K=128 ----
#pragma unroll
        for (int ks = 0; ks < 8; ++ks) {
            int kb = (ks << 1) | q;
            bf16x8 a = *(const bf16x8*)&af[ks];
#pragma unroll
            for (int tn = 0; tn < 4; ++tn) {
                bf16x8 b = ((const bf16x8*)Ws)[kb * 128 + tn * 32 + l31];
                acc[tn] = __builtin_amdgcn_mfma_f32_32x32x16_bf16(a, b, acc[tn], 0, 0, 0);
            }
        }
    }

    // ---- epilogue: store y + BN stats ----
#pragma unroll
    for (int tn = 0; tn < 4; ++tn) {
        int col = tn * 32 + l31;
        float s = 0.f, sq = 0.f;
#pragma unroll
        for (int r = 0; r < 16; ++r) {
            int rloc = (r & 3) + 8 * (r >> 2) + 4 * q + rw;
            int grow = m0 + rloc;
            float v = acc[tn][r];
            if (grow < M) yout[grow * 128 + col] = v;
            s += v; sq += v * v;
        }
        s += __shfl_xor(s, 32);
        sq += __shfl_xor(sq, 32);
        if (lane < 32) {
            atomicAdd(&stats[col], s);
            atomicAdd(&stats[128 + col], sq);
        }
    }
}

// ---------------------------------------------------------------------------
// BN (batch stats) + ReLU -> bf16 (optionally + residual)
// ---------------------------------------------------------------------------
__global__ void bn_relu_kernel(const float* __restrict__ y, const float* __restrict__ stats,
                               const float* __restrict__ g, const float* __restrict__ b,
                               unsigned short* __restrict__ out, int total4, float invM) {
    int idx = blockIdx.x * 256 + threadIdx.x;
    if (idx >= total4) return;
    int e0 = idx * 4;
    int c0 = e0 & 127;
    float4 yv = *(const float4*)(y + e0);
    float h[4];
    const float* yp = (const float*)&yv;
#pragma unroll
    for (int j = 0; j < 4; ++j) {
        int c = c0 + j;
        float mean = stats[c] * invM;
        float var = stats[128 + c] * invM - mean * mean;
        float sc = g[c] * rsqrtf(var + LN_EPS);
        float sh = b[c] - mean * sc;
        float vv = yp[j] * sc + sh;
        h[j] = vv > 0.f ? vv : 0.f;
    }
    uint2 pk;
    pk.x = f2bf_rne(h[0]) | (f2bf_rne(h[1]) << 16);
    pk.y = f2bf_rne(h[2]) | (f2bf_rne(h[3]) << 16);
    *(uint2*)(out + e0) = pk;
}

__global__ void bn_relu_res_kernel(const float* __restrict__ y, const float* __restrict__ stats,
                                   const float* __restrict__ g, const float* __restrict__ b,
                                   const unsigned short* __restrict__ idn,
                                   unsigned short* __restrict__ out, int total4, float invM) {
    int idx = blockIdx.x * 256 + threadIdx.x;
    if (idx >= total4) return;
    int e0 = idx * 4;
    int c0 = e0 & 127;
    float4 yv = *(const float4*)(y + e0);
    uint2 iv = *(const uint2*)(idn + e0);
    float id[4];
    id[0] = __uint_as_float(iv.x << 16);
    id[1] = __uint_as_float(iv.x & 0xffff0000u);
    id[2] = __uint_as_float(iv.y << 16);
    id[3] = __uint_as_float(iv.y & 0xffff0000u);
    float h[4];
    const float* yp = (const float*)&yv;
#pragma unroll
    for (int j = 0; j < 4; ++j) {
        int c = c0 + j;
        float mean = stats[c] * invM;
        float var = stats[128 + c] * invM - mean * mean;
        float sc = g[c] * rsqrtf(var + LN_EPS);
        float sh = b[c] - mean * sc;
        float vv = yp[j] * sc + sh + id[j];
        h[j] = vv > 0.f ? vv : 0.f;
    }
    uint2 pk;
    pk.x = f2bf_rne(h[0]) | (f2bf_rne(h[1]) << 16);
    pk.y = f2bf_rne(h[2]) | (f2bf_rne(h[3]) << 16);
    *(uint2*)(out + e0) = pk;
}

// ---------------------------------------------------------------------------
// Head: out = gp[:,:14] + relu(A[inv] @ w1 + b1) @ w2 + b2.  One wave/point.
// ---------------------------------------------------------------------------
__global__ __launch_bounds__(256) void head_kernel(
    const float* __restrict__ gp, const unsigned short* __restrict__ A,
    const int* __restrict__ inv_idx, const float* __restrict__ w1,
    const float* __restrict__ b1, const float* __restrict__ w2,
    const float* __restrict__ b2, float* __restrict__ out, int N)
{
    int p = blockIdx.x * 4 + (threadIdx.x >> 6);
    int lane = threadIdx.x & 63;
    if (p >= N) return;
    int vx = inv_idx[p];
    unsigned u = *(const unsigned*)(A + vx * 128 + lane * 2);
    float pf0 = __uint_as_float(u << 16);
    float pf1 = __uint_as_float(u & 0xffff0000u);
    float t = b1[lane];
#pragma unroll
    for (int c = 0; c < 128; c += 2) {
        float pa = __shfl(pf0, c >> 1);
        float pb = __shfl(pf1, c >> 1);
        t = fmaf(pa, w1[c * 64 + lane], t);
        t = fmaf(pb, w1[(c + 1) * 64 + lane], t);
    }
    t = t > 0.f ? t : 0.f;
    int cl = lane < 14 ? lane : 13;
    float o = b2[cl] + gp[p * 14 + cl];
#pragma unroll
    for (int k = 0; k < 64; ++k) {
        float tv = __shfl(t, k);
        o = fmaf(tv, w2[k * 14 + cl], o);
    }
    if (lane < 14) out[p * 14 + lane] = o;
}

// ---------------------------------------------------------------------------
extern "C" void kernel_launch(void* const* d_in, const int* in_sizes, int n_in,
                              void* d_out, int out_size, void* d_ws, size_t ws_size,
                              hipStream_t stream) {
    const float* gp       = (const float*)d_in[0];
    const float* w_enc    = (const float*)d_in[1];
    const float* b_enc    = (const float*)d_in[2];
    const float* ln_g     = (const float*)d_in[3];
    const float* ln_b     = (const float*)d_in[4];
    const float* conv_w   = (const float*)d_in[5];
    const float* bn_g     = (const float*)d_in[6];
    const float* bn_b     = (const float*)d_in[7];
    const float* w1       = (const float*)d_in[8];
    const float* b1       = (const float*)d_in[9];
    const float* w2       = (const float*)d_in[10];
    const float* b2       = (const float*)d_in[11];
    const float* nbr_mask = (const float*)d_in[12];
    const int*   inv_idx  = (const int*)d_in[13];
    const int*   nbr_idx  = (const int*)d_in[14];

    const int N = in_sizes[0] / 14;
    const int M = in_sizes[12] / 27;
    const int ntiles = (M + 127) / 128;

    char* ws = (char*)d_ws;
    size_t off = 0;
    unsigned short* Wp = (unsigned short*)(ws + off); off += (size_t)4 * 27 * 16384 * 2;
    unsigned short* A  = (unsigned short*)(ws + off); off += (size_t)(M + 1) * 128 * 2;
    unsigned short* H  = (unsigned short*)(ws + off); off += (size_t)(M + 1) * 128 * 2;
    // --- contiguous zeroed region: Yraw, cnt, stats, act ---
    float* Yraw  = (float*)(ws + off);
    size_t zoff = off;
    off += (size_t)M * 128 * 4;                      // Yraw / voxel-sum accumulator
    float* cnt   = (float*)(ws + off); off += (size_t)M * 4;
    float* stats = (float*)(ws + off); off += 4 * 256 * 4;
    unsigned* act = (unsigned*)(ws + off); off += (size_t)ntiles * 4;
    size_t zbytes = off - zoff;
    int* T = (int*)(ws + off); off += (size_t)27 * M * 4;

    hipMemsetAsync(Yraw, 0, zbytes, stream);
    hipMemsetAsync(A + (size_t)M * 128, 0, 256, stream);  // dummy zero rows
    hipMemsetAsync(H + (size_t)M * 128, 0, 256, stream);

    const int E = 4 * 27 * 128 * 128;
    pack_w_kernel<<<(E + 255) / 256, 256, 0, stream>>>(conv_w, Wp, E);
    prep_nbr_kernel<<<(M + 255) / 256, 256, 0, stream>>>(nbr_idx, nbr_mask, T, act, M);
    encode_kernel<<<(N + 3) / 4, 256, 0, stream>>>(gp, w_enc, b_enc, ln_g, ln_b, inv_idx, Yraw, cnt, N);
    const int total4 = M * 32;
    vox_mean_kernel<<<(total4 + 255) / 256, 256, 0, stream>>>(Yraw, cnt, A, total4);

    const float invM = 1.f / (float)M;
    for (int blk = 0; blk < 2; ++blk) {
        int c0 = 2 * blk, c1 = 2 * blk + 1;
        subm_conv_kernel<<<ntiles, 256, 0, stream>>>(
            A, Wp + (size_t)c0 * 27 * 16384, T, act, Yraw, stats + c0 * 256, M);
        bn_relu_kernel<<<(total4 + 255) / 256, 256, 0, stream>>>(
            Yraw, stats + c0 * 256, bn_g + c0 * 128, bn_b + c0 * 128, H, total4, invM);
        subm_conv_kernel<<<ntiles, 256, 0, stream>>>(
            H, Wp + (size_t)c1 * 27 * 16384, T, act, Yraw, stats + c1 * 256, M);
        bn_relu_res_kernel<<<(total4 + 255) / 256, 256, 0, stream>>>(
            Yraw, stats + c1 * 256, bn_g + c1 * 128, bn_b + c1 * 128, A, A, total4, invM);
    }
    head_kernel<<<(N + 3) / 4, 256, 0, stream>>>(gp, A, inv_idx, w1, b1, w2, b2, (float*)d_out, N);
}

// Round 3
// 1524.219 us; speedup vs baseline: 1.8233x; 1.2232x over previous
//
#include <hip/hip_runtime.h>

typedef __bf16 bf16x8 __attribute__((ext_vector_type(8)));
typedef float f32x16 __attribute__((ext_vector_type(16)));

#define LN_EPS 1e-5f
#define AS1 __attribute__((address_space(1)))
#define AS3 __attribute__((address_space(3)))

__device__ __forceinline__ unsigned f2bf_rne(float f) {
    unsigned x = __float_as_uint(f);
    return (x + 0x7fffu + ((x >> 16) & 1u)) >> 16;  // round-to-nearest-even, finite inputs
}

__device__ __forceinline__ float bf2f(unsigned short u) {
    return __uint_as_float((unsigned)u << 16);
}

// ---------------------------------------------------------------------------
// Pack conv_w fp32 (4,27,128,128) -> bf16, K-packed by 8: Wp[oc][k>>3][n][k&7]
// so MFMA B-fragments are contiguous 16B.
// ---------------------------------------------------------------------------
__global__ void pack_w_kernel(const float* __restrict__ cw, unsigned short* __restrict__ Wp, int E) {
    int idx = blockIdx.x * 256 + threadIdx.x;
    if (idx >= E) return;
    float v = cw[idx];
    int n  = idx & 127;
    int c  = (idx >> 7) & 127;
    int oc = idx >> 14;
    Wp[oc * 16384 + (c >> 3) * 1024 + n * 8 + (c & 7)] = (unsigned short)f2bf_rne(v);
}

// Pack w1 fp32 (128,64) -> bf16 K-packed: Wp1[k>>3][n][k&7], 8192 elems.
__global__ void pack_w1_kernel(const float* __restrict__ w1, unsigned short* __restrict__ Wp1) {
    int idx = blockIdx.x * 256 + threadIdx.x;
    if (idx >= 8192) return;
    int k = idx >> 6, n = idx & 63;
    Wp1[(k >> 3) * 512 + n * 8 + (k & 7)] = (unsigned short)f2bf_rne(w1[k * 64 + n]);
}

// ---------------------------------------------------------------------------
// Prep: gather table T[o][m] = found ? nbr_idx : M (dummy zero row),
// and per-128-tile activity bitmask act[tile].
// ---------------------------------------------------------------------------
__global__ void prep_nbr_kernel(const int* __restrict__ nbr_idx, const float* __restrict__ nbr_mask,
                                int* __restrict__ T, unsigned* __restrict__ act, int M) {
    int m = blockIdx.x * 256 + threadIdx.x;
    if (m >= M) return;
    unsigned bits = 0;
#pragma unroll
    for (int o = 0; o < 27; ++o) {
        bool f = nbr_mask[m * 27 + o] != 0.f;
        int g = f ? nbr_idx[m * 27 + o] : M;
        T[o * M + m] = g;
        bits |= (f ? 1u : 0u) << o;
    }
    atomicOr(&act[m >> 7], bits);
}

// ---------------------------------------------------------------------------
// Encoder: f = relu(LN(gp @ w_enc + b_enc)), scatter-add into voxel sums.
// ---------------------------------------------------------------------------
__global__ __launch_bounds__(256) void encode_kernel(
    const float* __restrict__ gp, const float* __restrict__ w_enc,
    const float* __restrict__ b_enc, const float* __restrict__ ln_g,
    const float* __restrict__ ln_b, const int* __restrict__ inv_idx,
    float* __restrict__ vsum, float* __restrict__ cnt, int N)
{
    int p = blockIdx.x * 4 + (threadIdx.x >> 6);
    int lane = threadIdx.x & 63;
    if (p >= N) return;
    float gv[14];
#pragma unroll
    for (int i = 0; i < 14; ++i) gv[i] = gp[p * 14 + i];
    float f0 = b_enc[lane], f1 = b_enc[lane + 64];
#pragma unroll
    for (int i = 0; i < 14; ++i) {
        f0 = fmaf(gv[i], w_enc[i * 128 + lane], f0);
        f1 = fmaf(gv[i], w_enc[i * 128 + lane + 64], f1);
    }
    float s = f0 + f1;
#pragma unroll
    for (int off = 32; off; off >>= 1) s += __shfl_xor(s, off);
    float mean = s * 0.0078125f;
    float d0 = f0 - mean, d1 = f1 - mean;
    float v = d0 * d0 + d1 * d1;
#pragma unroll
    for (int off = 32; off; off >>= 1) v += __shfl_xor(v, off);
    float rs = rsqrtf(v * 0.0078125f + LN_EPS);
    float h0 = d0 * rs * ln_g[lane] + ln_b[lane];
    float h1 = d1 * rs * ln_g[lane + 64] + ln_b[lane + 64];
    h0 = h0 > 0.f ? h0 : 0.f;
    h1 = h1 > 0.f ? h1 : 0.f;
    int vx = inv_idx[p];
    atomicAdd(&vsum[vx * 128 + lane], h0);
    atomicAdd(&vsum[vx * 128 + lane + 64], h1);
    if (lane == 0) atomicAdd(&cnt[vx], 1.0f);
}

// ---------------------------------------------------------------------------
// Voxel mean: A_bf16 = vsum / cnt
// ---------------------------------------------------------------------------
__global__ void vox_mean_kernel(const float* __restrict__ vsum, const float* __restrict__ cnt,
                                unsigned short* __restrict__ out, int total4) {
    int idx = blockIdx.x * 256 + threadIdx.x;
    if (idx >= total4) return;
    int e0 = idx * 4;
    float r = 1.f / cnt[e0 >> 7];
    float4 v = *(const float4*)(vsum + e0);
    uint2 pk;
    pk.x = f2bf_rne(v.x * r) | (f2bf_rne(v.y * r) << 16);
    pk.y = f2bf_rne(v.z * r) | (f2bf_rne(v.w * r) << 16);
    *(uint2*)(out + e0) = pk;
}

// ---------------------------------------------------------------------------
// Submanifold conv: y[m] = sum_o x[T[o][m]] @ W[o]   (T==M -> zero row)
// 128 voxels x 128 ch per block, 4 waves. A gathered straight to registers
// (no LDS), W[o] staged async via global_load_lds. Tile-level offset skip
// via precomputed bitmask.
// ---------------------------------------------------------------------------
__global__ __launch_bounds__(256, 4) void subm_conv_kernel(
    const unsigned short* __restrict__ xin,   // (M+1) x 128 bf16, row M zeros
    const unsigned short* __restrict__ Wp,    // 27 x 16 x 128 x 8 bf16 packed
    const int* __restrict__ T, const unsigned* __restrict__ act,
    float* __restrict__ yout, float* __restrict__ stats, int M)
{
    __shared__ uint4 Ws[2048];  // W[o]: [kb][n] 16B chunks, 32 KB

    const int tid = threadIdx.x;
    const int lane = tid & 63;
    const int w = tid >> 6;
    const int m0 = blockIdx.x * 128;
    const int rw = w * 32;
    const int q = lane >> 5;
    const int l31 = lane & 31;
    int myrow = m0 + rw + l31;
    if (myrow >= M) myrow = M - 1;  // gather table guard (stores guarded below)

    f32x16 acc[4];
#pragma unroll
    for (int t = 0; t < 4; ++t)
#pragma unroll
        for (int r = 0; r < 16; ++r) acc[t][r] = 0.f;

    const uint4* xin4 = (const uint4*)xin;
    unsigned amask = act[blockIdx.x];

    while (amask) {
        int o = __ffs(amask) - 1;
        amask &= amask - 1;

        __syncthreads();  // Ws free (prev offset's MFMA reads done)

        // ---- async stage W[o] -> LDS (no VGPR cost) ----
        const uint4* WpO4 = (const uint4*)Wp + o * 2048;
#pragma unroll
        for (int rep = 0; rep < 8; ++rep) {
            __builtin_amdgcn_global_load_lds(
                (const AS1 unsigned int*)(WpO4 + rep * 256 + tid),
                (AS3 unsigned int*)(Ws + rep * 256 + w * 64), 16, 0, 0);
        }

        // ---- gather this wave's 32 A-rows straight to registers ----
        int g = T[o * M + myrow];
        uint4 af[8];
#pragma unroll
        for (int j = 0; j < 8; ++j) af[j] = xin4[g * 16 + 2 * j + q];

        __syncthreads();  // barrier drains vmcnt: W in LDS

        // ---- MFMA over K=128 ----
#pragma unroll
        for (int ks = 0; ks < 8; ++ks) {
            int kb = (ks << 1) | q;
            bf16x8 a = *(const bf16x8*)&af[ks];
#pragma unroll
            for (int tn = 0; tn < 4; ++tn) {
                bf16x8 b = ((const bf16x8*)Ws)[kb * 128 + tn * 32 + l31];
                acc[tn] = __builtin_amdgcn_mfma_f32_32x32x16_bf16(a, b, acc[tn], 0, 0, 0);
            }
        }
    }

    // ---- epilogue: store y + BN stats ----
#pragma unroll
    for (int tn = 0; tn < 4; ++tn) {
        int col = tn * 32 + l31;
        float s = 0.f, sq = 0.f;
#pragma unroll
        for (int r = 0; r < 16; ++r) {
            int rloc = (r & 3) + 8 * (r >> 2) + 4 * q + rw;
            int grow = m0 + rloc;
            float v = acc[tn][r];
            if (grow < M) yout[grow * 128 + col] = v;
            s += v; sq += v * v;
        }
        s += __shfl_xor(s, 32);
        sq += __shfl_xor(sq, 32);
        if (lane < 32) {
            atomicAdd(&stats[col], s);
            atomicAdd(&stats[128 + col], sq);
        }
    }
}

// ---------------------------------------------------------------------------
// BN (batch stats) + ReLU -> bf16 (optionally + residual)
// ---------------------------------------------------------------------------
__global__ void bn_relu_kernel(const float* __restrict__ y, const float* __restrict__ stats,
                               const float* __restrict__ g, const float* __restrict__ b,
                               unsigned short* __restrict__ out, int total4, float invM) {
    int idx = blockIdx.x * 256 + threadIdx.x;
    if (idx >= total4) return;
    int e0 = idx * 4;
    int c0 = e0 & 127;
    float4 yv = *(const float4*)(y + e0);
    float h[4];
    const float* yp = (const float*)&yv;
#pragma unroll
    for (int j = 0; j < 4; ++j) {
        int c = c0 + j;
        float mean = stats[c] * invM;
        float var = stats[128 + c] * invM - mean * mean;
        float sc = g[c] * rsqrtf(var + LN_EPS);
        float sh = b[c] - mean * sc;
        float vv = yp[j] * sc + sh;
        h[j] = vv > 0.f ? vv : 0.f;
    }
    uint2 pk;
    pk.x = f2bf_rne(h[0]) | (f2bf_rne(h[1]) << 16);
    pk.y = f2bf_rne(h[2]) | (f2bf_rne(h[3]) << 16);
    *(uint2*)(out + e0) = pk;
}

__global__ void bn_relu_res_kernel(const float* __restrict__ y, const float* __restrict__ stats,
                                   const float* __restrict__ g, const float* __restrict__ b,
                                   const unsigned short* __restrict__ idn,
                                   unsigned short* __restrict__ out, int total4, float invM) {
    int idx = blockIdx.x * 256 + threadIdx.x;
    if (idx >= total4) return;
    int e0 = idx * 4;
    int c0 = e0 & 127;
    float4 yv = *(const float4*)(y + e0);
    uint2 iv = *(const uint2*)(idn + e0);
    float id[4];
    id[0] = __uint_as_float(iv.x << 16);
    id[1] = __uint_as_float(iv.x & 0xffff0000u);
    id[2] = __uint_as_float(iv.y << 16);
    id[3] = __uint_as_float(iv.y & 0xffff0000u);
    float h[4];
    const float* yp = (const float*)&yv;
#pragma unroll
    for (int j = 0; j < 4; ++j) {
        int c = c0 + j;
        float mean = stats[c] * invM;
        float var = stats[128 + c] * invM - mean * mean;
        float sc = g[c] * rsqrtf(var + LN_EPS);
        float sh = b[c] - mean * sc;
        float vv = yp[j] * sc + sh + id[j];
        h[j] = vv > 0.f ? vv : 0.f;
    }
    uint2 pk;
    pk.x = f2bf_rne(h[0]) | (f2bf_rne(h[1]) << 16);
    pk.y = f2bf_rne(h[2]) | (f2bf_rne(h[3]) << 16);
    *(uint2*)(out + e0) = pk;
}

// ---------------------------------------------------------------------------
// Head over voxels: Dv = relu(A @ w1 + b1) @ w2   (per-voxel, M x 14)
// Layer1: MFMA 128x64 tile. Layer2: LDS round-trip, vector dot K=64.
// ---------------------------------------------------------------------------
__global__ __launch_bounds__(256) void head_vox_kernel(
    const unsigned short* __restrict__ A,    // (M+1) x 128 bf16
    const unsigned short* __restrict__ Wp1,  // 8 x 64 x 8 bf16 packed
    const float* __restrict__ b1, const float* __restrict__ w2,
    const float* __restrict__ b2, float* __restrict__ Dv, int M)
{
    __shared__ uint4 W1s[1024];          // 16 KB
    __shared__ unsigned short Hs[8192];  // 128 x 64 bf16, chunk-swizzled, 16 KB
    __shared__ float w2s[896];           // 64 x 14

    const int tid = threadIdx.x;
    const int lane = tid & 63;
    const int w = tid >> 6;
    const int m0 = blockIdx.x * 128;
    const int rw = w * 32;
    const int q = lane >> 5;
    const int l31 = lane & 31;
    int myrow = m0 + rw + l31;
    if (myrow > M) myrow = M;  // row M is zeros

    // stage w1 (async) + w2 (regular)
#pragma unroll
    for (int rep = 0; rep < 4; ++rep) {
        __builtin_amdgcn_global_load_lds(
            (const AS1 unsigned int*)((const uint4*)Wp1 + rep * 256 + tid),
            (AS3 unsigned int*)(W1s + rep * 256 + w * 64), 16, 0, 0);
    }
    for (int i = tid; i < 896; i += 256) w2s[i] = w2[i];

    // A rows straight to registers
    const uint4* xin4 = (const uint4*)A;
    uint4 af[8];
#pragma unroll
    for (int j = 0; j < 8; ++j) af[j] = xin4[myrow * 16 + 2 * j + q];

    f32x16 acc[2];
#pragma unroll
    for (int t = 0; t < 2; ++t)
#pragma unroll
        for (int r = 0; r < 16; ++r) acc[t][r] = 0.f;

    __syncthreads();  // drains vmcnt: w1 in LDS

#pragma unroll
    for (int ks = 0; ks < 8; ++ks) {
        int kb = (ks << 1) | q;
        bf16x8 a = *(const bf16x8*)&af[ks];
#pragma unroll
        for (int tn = 0; tn < 2; ++tn) {
            bf16x8 b = ((const bf16x8*)W1s)[kb * 64 + tn * 32 + l31];
            acc[tn] = __builtin_amdgcn_mfma_f32_32x32x16_bf16(a, b, acc[tn], 0, 0, 0);
        }
    }

    // relu + bias -> Hs (bf16, chunk-swizzled: chunk' = chunk ^ (row&7))
#pragma unroll
    for (int tn = 0; tn < 2; ++tn) {
        int col = tn * 32 + l31;
        float bias = b1[col];
        int ch = col >> 3, ce = col & 7;
#pragma unroll
        for (int r = 0; r < 16; ++r) {
            int rloc = (r & 3) + 8 * (r >> 2) + 4 * q + rw;
            float v = acc[tn][r] + bias;
            v = v > 0.f ? v : 0.f;
            Hs[rloc * 64 + (ch ^ (rloc & 7)) * 8 + ce] = (unsigned short)f2bf_rne(v);
        }
    }
    __syncthreads();

    // layer 2: thread -> (row = tid>>1, 7 cols)
    int r2 = tid >> 1;
    int c0 = (tid & 1) * 7;
    float o[7];
#pragma unroll
    for (int j = 0; j < 7; ++j) o[j] = b2[c0 + j];
#pragma unroll
    for (int c = 0; c < 8; ++c) {
        bf16x8 hv = ((const bf16x8*)Hs)[r2 * 8 + (c ^ (r2 & 7))];
#pragma unroll
        for (int e = 0; e < 8; ++e) {
            float h = bf2f(((const unsigned short*)&hv)[e]);
            int k = c * 8 + e;
#pragma unroll
            for (int j = 0; j < 7; ++j) o[j] = fmaf(h, w2s[k * 14 + c0 + j], o[j]);
        }
    }
    int grow = m0 + r2;
    if (grow < M) {
#pragma unroll
        for (int j = 0; j < 7; ++j) Dv[grow * 14 + c0 + j] = o[j];
    }
}

// out[p] = gp[p,:14] + Dv[inv_idx[p]]
__global__ void head_scatter_kernel(const float* __restrict__ gp, const float* __restrict__ Dv,
                                    const int* __restrict__ inv_idx, float* __restrict__ out, int N) {
    int p = blockIdx.x * 256 + threadIdx.x;
    if (p >= N) return;
    int vx = inv_idx[p];
#pragma unroll
    for (int c = 0; c < 14; ++c) out[p * 14 + c] = gp[p * 14 + c] + Dv[vx * 14 + c];
}

// ---------------------------------------------------------------------------
extern "C" void kernel_launch(void* const* d_in, const int* in_sizes, int n_in,
                              void* d_out, int out_size, void* d_ws, size_t ws_size,
                              hipStream_t stream) {
    const float* gp       = (const float*)d_in[0];
    const float* w_enc    = (const float*)d_in[1];
    const float* b_enc    = (const float*)d_in[2];
    const float* ln_g     = (const float*)d_in[3];
    const float* ln_b     = (const float*)d_in[4];
    const float* conv_w   = (const float*)d_in[5];
    const float* bn_g     = (const float*)d_in[6];
    const float* bn_b     = (const float*)d_in[7];
    const float* w1       = (const float*)d_in[8];
    const float* b1       = (const float*)d_in[9];
    const float* w2       = (const float*)d_in[10];
    const float* b2       = (const float*)d_in[11];
    const float* nbr_mask = (const float*)d_in[12];
    const int*   inv_idx  = (const int*)d_in[13];
    const int*   nbr_idx  = (const int*)d_in[14];

    const int N = in_sizes[0] / 14;
    const int M = in_sizes[12] / 27;
    const int ntiles = (M + 127) / 128;

    char* ws = (char*)d_ws;
    size_t off = 0;
    unsigned short* Wp = (unsigned short*)(ws + off); off += (size_t)4 * 27 * 16384 * 2;
    unsigned short* A  = (unsigned short*)(ws + off); off += (size_t)(M + 1) * 128 * 2;
    unsigned short* H  = (unsigned short*)(ws + off); off += (size_t)(M + 1) * 128 * 2;
    // --- contiguous zeroed region: Yraw, cnt, stats, act ---
    float* Yraw  = (float*)(ws + off);
    size_t zoff = off;
    off += (size_t)M * 128 * 4;                      // Yraw / voxel sums; later reused as Dv
    float* cnt   = (float*)(ws + off); off += (size_t)M * 4;
    float* stats = (float*)(ws + off); off += 4 * 256 * 4;
    unsigned* act = (unsigned*)(ws + off); off += (size_t)ntiles * 4;
    size_t zbytes = off - zoff;
    int* T = (int*)(ws + off); off += (size_t)27 * M * 4;
    unsigned short* Wp1 = (unsigned short*)(ws + off); off += 8192 * 2;
    float* Dv = Yraw;  // reuse: Yraw free after last bn_relu_res

    hipMemsetAsync(Yraw, 0, zbytes, stream);
    hipMemsetAsync(A + (size_t)M * 128, 0, 256, stream);  // dummy zero rows
    hipMemsetAsync(H + (size_t)M * 128, 0, 256, stream);

    const int E = 4 * 27 * 128 * 128;
    pack_w_kernel<<<(E + 255) / 256, 256, 0, stream>>>(conv_w, Wp, E);
    pack_w1_kernel<<<32, 256, 0, stream>>>(w1, Wp1);
    prep_nbr_kernel<<<(M + 255) / 256, 256, 0, stream>>>(nbr_idx, nbr_mask, T, act, M);
    encode_kernel<<<(N + 3) / 4, 256, 0, stream>>>(gp, w_enc, b_enc, ln_g, ln_b, inv_idx, Yraw, cnt, N);
    const int total4 = M * 32;
    vox_mean_kernel<<<(total4 + 255) / 256, 256, 0, stream>>>(Yraw, cnt, A, total4);

    const float invM = 1.f / (float)M;
    for (int blk = 0; blk < 2; ++blk) {
        int c0 = 2 * blk, c1 = 2 * blk + 1;
        subm_conv_kernel<<<ntiles, 256, 0, stream>>>(
            A, Wp + (size_t)c0 * 27 * 16384, T, act, Yraw, stats + c0 * 256, M);
        bn_relu_kernel<<<(total4 + 255) / 256, 256, 0, stream>>>(
            Yraw, stats + c0 * 256, bn_g + c0 * 128, bn_b + c0 * 128, H, total4, invM);
        subm_conv_kernel<<<ntiles, 256, 0, stream>>>(
            H, Wp + (size_t)c1 * 27 * 16384, T, act, Yraw, stats + c1 * 256, M);
        bn_relu_res_kernel<<<(total4 + 255) / 256, 256, 0, stream>>>(
            Yraw, stats + c1 * 256, bn_g + c1 * 128, bn_b + c1 * 128, A, A, total4, invM);
    }
    head_vox_kernel<<<ntiles, 256, 0, stream>>>(A, Wp1, b1, w2, b2, Dv, M);
    head_scatter_kernel<<<(N + 255) / 256, 256, 0, stream>>>(gp, Dv, inv_idx, (float*)d_out, N);
}